// Round 4
// baseline (11612.678 us; speedup 1.0000x reference)
//
#include <hip/hip_runtime.h>
#include <math.h>

// ---------------------------------------------------------------------------
// SynchronAutoencoder: 3 stacked synchron-GRU layers, W=512, C=16.
// R4: per-wave autonomous recurrent steps (no __syncthreads / no LDS in the
// 512-step loop). Wave w of WG g owns unit u=8g+w: polls encoded h (base
// alternates 2/8 by (s>>1)&1, ping-pong parity buffers), 24 FMA over its
// contiguous lane fragment (k=8l..8l+7), 3 xor-butterfly reduces (sum in all
// lanes), gates computed redundantly in all lanes, lane 0 stores h+base.
// WAR induction holds at wave granularity: a wave writes h_{s+1} only after
// consuming ALL of h_s, which requires every wave to have finished s-1.
// Chain phase = separate kernel, same broadcast structure: write-once ybuf
// slot per link (base 2), kc column-weights issued before the poll (overlap).
// Replaces R3's split-K partials (47 MB write-through + fan-in-64 reduce).
// ---------------------------------------------------------------------------

#define AGENT __HIP_MEMORY_SCOPE_AGENT
#define NWG   64

__device__ __forceinline__ float f32_ld(const float* p) {
  return __hip_atomic_load((float*)p, __ATOMIC_RELAXED, AGENT);
}
__device__ __forceinline__ void f32_st(float* p, float v) {
  __hip_atomic_store(p, v, __ATOMIC_RELAXED, AGENT);
}
__device__ __forceinline__ unsigned long long u64_ld(const unsigned long long* p) {
  return __hip_atomic_load((unsigned long long*)p, __ATOMIC_RELAXED, AGENT);
}
__device__ __forceinline__ float loF(unsigned long long u) {
  return __builtin_bit_cast(float, (unsigned)(u & 0xffffffffull));
}
__device__ __forceinline__ float hiF(unsigned long long u) {
  return __builtin_bit_cast(float, (unsigned)(u >> 32));
}
__device__ __forceinline__ float sigm(float x) { return 1.f / (1.f + __expf(-x)); }
__device__ __forceinline__ float tanh_f(float x) {
  float e = __expf(2.f * x);
  return 1.f - 2.f / (e + 1.f);
}

// ---- KA1: chain step-1 hidden state h1[i][u] (parallel, reads kc) ----------
__global__ void ka1_kernel(const float* __restrict__ xin, const float* __restrict__ kc,
                           const float* __restrict__ bc, float* __restrict__ h1) {
  __shared__ float x1s[512];
  __shared__ float red[8][3][32];
  const int tid = threadIdx.x;
  x1s[tid]       = xin[tid * 16 + 1];
  x1s[tid + 256] = xin[(tid + 256) * 16 + 1];
  __syncthreads();
  const int i  = blockIdx.x >> 4;
  const int ub = (blockIdx.x & 15) << 5;
  const int s = tid >> 5, c = tid & 31;
  const float* base = kc + (size_t)i * 786432 + ub + c;
  float a0 = 0.f, a1 = 0.f, a2 = 0.f;
  const int kk = s * 64;
  for (int k = kk; k < kk + 64; ++k) {
    const float xv = x1s[k];
    const float* row = base + (size_t)k * 1536;
    a0 = fmaf(xv, row[0],    a0);
    a1 = fmaf(xv, row[512],  a1);
    a2 = fmaf(xv, row[1024], a2);
  }
  red[s][0][c] = a0; red[s][1][c] = a1; red[s][2][c] = a2;
  __syncthreads();
  if (tid < 32) {
    const int u = tid;
    float g0 = 0.f, g1 = 0.f, g2 = 0.f;
    for (int ss = 0; ss < 8; ++ss) { g0 += red[ss][0][u]; g1 += red[ss][1][u]; g2 += red[ss][2][u]; }
    const float* bi = bc + (size_t)i * 3072;
    const float* br = bi + 1536;
    const int cz = ub + u, cr = 512 + ub + u, cn = 1024 + ub + u;
    const float z1  = sigm(g0 + bi[cz] + br[cz]);
    const float r1  = sigm(g1 + bi[cr] + br[cr]);
    const float hh1 = tanh_f(g2 + bi[cn] + r1 * br[cn]);
    h1[i * 512 + ub + u] = (1.f - z1) * hh1;
  }
}

// ---- KA2: gh2[i][col] = h1[i] @ rkc[i] + b_r[col] (parallel, reads rkc) ----
__global__ void ka2_kernel(const float* __restrict__ h1, const float* __restrict__ rkc,
                           const float* __restrict__ bc, float* __restrict__ gh2) {
  __shared__ float hs[512];
  __shared__ float red[4][64];
  const int tid = threadIdx.x;
  const int i  = blockIdx.x / 24;
  const int cb = (blockIdx.x % 24) << 6;
  hs[tid]       = h1[i * 512 + tid];
  hs[tid + 256] = h1[i * 512 + tid + 256];
  __syncthreads();
  const int s = tid >> 6, c = tid & 63;
  const float* base = rkc + (size_t)i * 786432 + cb + c;
  float acc = 0.f;
  const int kk = s * 128;
  for (int k = kk; k < kk + 128; ++k) acc = fmaf(hs[k], base[(size_t)k * 1536], acc);
  red[s][c] = acc;
  __syncthreads();
  if (tid < 64) {
    const float v = red[0][tid] + red[1][tid] + red[2][tid] + red[3][tid];
    gh2[i * 1536 + cb + tid] = v + bc[(size_t)i * 3072 + 1536 + cb + tid];
  }
}

// ---- KRC_REC: 512 sequential GRU0 steps, per-wave autonomous ---------------
__global__ __launch_bounds__(512, 1) void krc_rec(
    const float* __restrict__ xin, const float* __restrict__ k0,
    const float* __restrict__ rk0, const float* __restrict__ b0,
    float* __restrict__ lout, float* hbuf, float* y0buf) {
  __shared__ float x0l[512];
  const int tid = threadIdx.x, g = blockIdx.x;
  const int wave = tid >> 6, lane = tid & 63;
  const int u = g * 8 + wave;

  x0l[tid] = xin[tid * 16];
  // recurrent weights: w[gate][j] = rk0[(8*lane+j)][gate*512 + u]
  float w[3][8];
  {
    const float* rb = rk0 + (size_t)(8 * lane) * 1536 + u;
#pragma unroll
    for (int p = 0; p < 3; ++p)
#pragma unroll
      for (int j = 0; j < 8; ++j)
        w[p][j] = rb[(size_t)j * 1536 + p * 512];
  }
  const float k0z = k0[u],        k0r = k0[512 + u],  k0n  = k0[1024 + u];
  const float biz = b0[u],        bir = b0[512 + u],  bin_ = b0[1024 + u];
  const float brz = b0[1536 + u], brr = b0[2048 + u], brn  = b0[2560 + u];
  __syncthreads();   // x0l ready; loop below is sync-free

  float hprev = 0.f;   // unit u's h, identical in all lanes of the wave
  for (int s = 0; s < 512; ++s) {
    float vz = 0.f, vr = 0.f, vn = 0.f;
    if (s) {
      const float base = ((s >> 1) & 1) ? 8.f : 2.f;
      const unsigned long long* bp =
          (const unsigned long long*)(hbuf + ((s & 1) << 9)) + 4 * lane;
      float hA[8]; bool ok;
      do {
        const unsigned long long a0 = u64_ld(bp),     a1 = u64_ld(bp + 1);
        const unsigned long long a2 = u64_ld(bp + 2), a3 = u64_ld(bp + 3);
        hA[0] = loF(a0); hA[1] = hiF(a0); hA[2] = loF(a1); hA[3] = hiF(a1);
        hA[4] = loF(a2); hA[5] = hiF(a2); hA[6] = loF(a3); hA[7] = hiF(a3);
        ok = true;
#pragma unroll
        for (int j = 0; j < 8; ++j) ok = ok && (__builtin_fabsf(hA[j] - base) < 1.25f);
      } while (!__all(ok));
#pragma unroll
      for (int j = 0; j < 8; ++j) {
        const float h = hA[j] - base;
        vz = fmaf(h, w[0][j], vz); vr = fmaf(h, w[1][j], vr); vn = fmaf(h, w[2][j], vn);
      }
#pragma unroll
      for (int m = 1; m < 64; m <<= 1) {
        vz += __shfl_xor(vz, m); vr += __shfl_xor(vr, m); vn += __shfl_xor(vn, m);
      }
    }
    const float xt = x0l[s];
    const float z  = sigm(fmaf(xt, k0z, biz) + vz + brz);
    const float r  = sigm(fmaf(xt, k0r, bir) + vr + brr);
    const float hh = tanh_f(fmaf(xt, k0n, bin_) + r * (vn + brn));
    const float hnew = z * hprev + (1.f - z) * hh;
    hprev = hnew;
    if (lane == 0) {
      if (s < 511) {
        const float nb = (((s + 1) >> 1) & 1) ? 8.f : 2.f;
        f32_st(&hbuf[(((s + 1) & 1) << 9) + u], hnew + nb);
      } else {
        lout[u] = hnew;                 // y0
        f32_st(&y0buf[u], hnew + 2.f);  // chain slot 0 (encoded)
      }
    }
  }
}

// ---- KRC_CHAIN: 15 sequential chain links, broadcast-y structure -----------
__global__ __launch_bounds__(512, 1) void krc_chain(
    const float* __restrict__ kc, const float* __restrict__ bc,
    const float* __restrict__ h1, const float* __restrict__ gh2,
    float* __restrict__ lout, float* ybuf) {
  __shared__ float ccon[15 * 56];   // [ci][field(7)][unit8]
  const int tid = threadIdx.x, g = blockIdx.x;
  const int wave = tid >> 6, lane = tid & 63;
  const int u = g * 8 + wave;

  for (int idx = tid; idx < 15 * 56; idx += 512) {
    const int ci = idx / 56, r = idx - ci * 56;
    const int f = r >> 3, uu = g * 8 + (r & 7);
    float v;
    if (f < 3)      v = bc[(size_t)ci * 3072 + f * 512 + uu];
    else if (f < 6) v = gh2[ci * 1536 + (f - 3) * 512 + uu];
    else            v = h1[ci * 512 + uu];
    ccon[idx] = v;
  }
  __syncthreads();

  for (int ci = 0; ci < 15; ++ci) {
    // issue weight loads first so they overlap the poll RTT
    float wv[3][8];
    {
      const float* kb = kc + (size_t)ci * 786432 + (size_t)(8 * lane) * 1536 + u;
#pragma unroll
      for (int p = 0; p < 3; ++p)
#pragma unroll
        for (int j = 0; j < 8; ++j)
          wv[p][j] = kb[(size_t)j * 1536 + p * 512];
    }
    const unsigned long long* bp =
        (const unsigned long long*)(ybuf + ci * 512) + 4 * lane;
    float yv[8]; bool ok;
    do {
      const unsigned long long a0 = u64_ld(bp),     a1 = u64_ld(bp + 1);
      const unsigned long long a2 = u64_ld(bp + 2), a3 = u64_ld(bp + 3);
      yv[0] = loF(a0); yv[1] = hiF(a0); yv[2] = loF(a1); yv[3] = hiF(a1);
      yv[4] = loF(a2); yv[5] = hiF(a2); yv[6] = loF(a3); yv[7] = hiF(a3);
      ok = true;
#pragma unroll
      for (int j = 0; j < 8; ++j) ok = ok && (__builtin_fabsf(yv[j] - 2.f) < 1.25f);
    } while (!__all(ok));
    float vz = 0.f, vr = 0.f, vn = 0.f;
#pragma unroll
    for (int j = 0; j < 8; ++j) {
      const float y = yv[j] - 2.f;
      vz = fmaf(y, wv[0][j], vz); vr = fmaf(y, wv[1][j], vr); vn = fmaf(y, wv[2][j], vn);
    }
#pragma unroll
    for (int m = 1; m < 64; m <<= 1) {
      vz += __shfl_xor(vz, m); vr += __shfl_xor(vr, m); vn += __shfl_xor(vn, m);
    }
    const float* cc = &ccon[ci * 56];
    const float z  = sigm(vz + cc[wave]      + cc[24 + wave]);
    const float r  = sigm(vr + cc[8 + wave]  + cc[32 + wave]);
    const float hh = tanh_f(vn + cc[16 + wave] + r * cc[40 + wave]);
    const float hnew = z * cc[48 + wave] + (1.f - z) * hh;
    if (lane == 0) {
      lout[(ci + 1) * 512 + u] = hnew;
      if (ci < 14) f32_st(&ybuf[(ci + 1) * 512 + u], hnew + 2.f);
    }
  }
}

// ---------------------------------------------------------------------------
// d_ws layout (floats; per-layer comm regions so stale-but-valid encoded
// values can't leak across layers):
//   hbuf: 3 * 1024      @ 0        (ping-pong h, encoded)
//   ybuf: 3 * 16*512    @ 3072     (write-once chain slots, encoded base 2)
//   h1:   15*512        @ 27648
//   gh2:  15*1536       @ 35328
//   lay1: 8192          @ 58368
//   lay2: 8192          @ 66560    (total ~300 KB)
// 0xAA poison decodes to -3.03e-13 -> outside every window.  No memset needed.
// ---------------------------------------------------------------------------
extern "C" void kernel_launch(void* const* d_in, const int* in_sizes, int n_in,
                              void* d_out, int out_size, void* d_ws, size_t ws_size,
                              hipStream_t stream) {
  (void)in_sizes; (void)n_in; (void)out_size; (void)ws_size;
  const float* x = (const float*)d_in[0];
  float* F    = (float*)d_ws;
  float* hbuf = F;                 // 3*1024
  float* ybuf = F + 3072;          // 3*8192
  float* h1   = F + 27648;         // 7680
  float* gh2  = F + 35328;         // 23040
  float* lay1 = F + 58368;         // 8192
  float* lay2 = F + 66560;         // 8192
  float* outf = (float*)d_out;

  const float* lin = x;
  float* louts[3] = {lay1, lay2, outf};
  for (int l = 0; l < 3; ++l) {
    const float* k0  = (const float*)d_in[1 + 6 * l + 0];
    const float* rk0 = (const float*)d_in[1 + 6 * l + 1];
    const float* b0  = (const float*)d_in[1 + 6 * l + 2];
    const float* kc  = (const float*)d_in[1 + 6 * l + 3];
    const float* rkc = (const float*)d_in[1 + 6 * l + 4];
    const float* bc  = (const float*)d_in[1 + 6 * l + 5];
    ka1_kernel<<<240, 256, 0, stream>>>(lin, kc, bc, h1);
    ka2_kernel<<<360, 256, 0, stream>>>(h1, rkc, bc, gh2);
    krc_rec<<<NWG, 512, 0, stream>>>(lin, k0, rk0, b0, louts[l],
                                     hbuf + l * 1024, ybuf + l * 8192);
    krc_chain<<<NWG, 512, 0, stream>>>(kc, bc, h1, gh2, louts[l],
                                       ybuf + (size_t)l * 8192);
    lin = louts[l];
  }
}